// Round 8
// baseline (190.496 us; speedup 1.0000x reference)
//
#include <hip/hip_runtime.h>
#include <stdint.h>

typedef __attribute__((ext_vector_type(8))) short  bf16x8;
typedef __attribute__((ext_vector_type(4))) short  short4v;
typedef __attribute__((ext_vector_type(4))) float  f32x4;
typedef __attribute__((ext_vector_type(4))) float  float4v;

#define VMW(N) asm volatile("s_waitcnt vmcnt(" #N ")" ::: "memory")
#define LKW(N) asm volatile("s_waitcnt lgkmcnt(" #N ")" ::: "memory")
#define BAR()  asm volatile("s_barrier" ::: "memory")

__device__ __forceinline__ short f2bf(float f) {
  union { float f; uint32_t u; } c; c.f = f;
  uint32_t u = c.u;
  uint32_t r = (u + 0x7FFFu + ((u >> 16) & 1u)) >> 16;
  return (short)(uint16_t)r;
}

__device__ __forceinline__ void gload_lds16(const void* g, void* l) {
  __builtin_amdgcn_global_load_lds(
      (const __attribute__((address_space(1))) void*)g,
      (__attribute__((address_space(3))) void*)l, 16, 0, 0);
}

// ---------------- f32 -> bf16 (vectorized, 4 elems/thread) ----------------
__global__ __launch_bounds__(256) void k_f32_to_bf16(
    const float* __restrict__ in, short* __restrict__ out, int n4) {
  int i = blockIdx.x * 256 + threadIdx.x;
  if (i >= n4) return;
  float4v v = *(const float4v*)(in + (size_t)i * 4);
  short4v o;
  o.x = f2bf(v.x); o.y = f2bf(v.y); o.z = f2bf(v.z); o.w = f2bf(v.w);
  *(short4v*)(out + (size_t)i * 4) = o;
}

// ------------- transpose f32[R][C] -> bf16[C][R] (64x64 LDS tiles) -------------
__global__ __launch_bounds__(256) void k_transpose_bf16(
    const float* __restrict__ in, short* __restrict__ out, int R, int C) {
  __shared__ short tile[64][65];
  int bc = blockIdx.x * 64, br = blockIdx.y * 64;
  int tc = threadIdx.x & 63, tr = threadIdx.x >> 6;  // tr 0..3
#pragma unroll
  for (int i = 0; i < 64; i += 4)
    tile[tc][tr + i] = f2bf(in[(size_t)(br + tr + i) * C + bc + tc]);
  __syncthreads();
#pragma unroll
  for (int i = 0; i < 64; i += 4)
    out[(size_t)(bc + tr + i) * R + br + tc] = tile[tr + i][tc];
}

// ---------- GEMM 256x256 8-phase (m201 template): C = A * BT^T + bias ----------
// BK=64, 512 threads = 8 waves (2M x 4N), per-wave C = 128x64 (acc[8][4]).
// LDS: per matrix [2 dbuf][2 M-half][128][64] shorts = 64 KB; total 128 KB.
// 128 KB LDS => exactly 1 block/CU = 2 waves/SIMD, so declare
// __launch_bounds__(512, 2) to unlock the 256-VGPR budget (R7 post-mortem:
// without it the allocator capped at 112 VGPR and spilled acc -> +35 MB
// WRITE_SIZE of scratch traffic).
// Per K-tile t: 4 phases; phase p reads af[mf=2p,2p+1] (+ all bf at p0),
// stages tile t+1 halves at p0/p1 (buf^1), 16 MFMA per phase between barriers.
// vmcnt(0) only at p3 — waits on loads issued >=2 phases earlier.
// Swizzle: LDS 16B-slot holds global octet slot^(row&7), both sides (rule #21).
template <bool F32OUT>
__global__ __launch_bounds__(512, 2) void k_g256(
    const short* __restrict__ A, const short* __restrict__ BT,
    const float* __restrict__ bias, void* __restrict__ Cout,
    int M, int N, int K, int nbn) {
  __shared__ short As[2][2][128][64];
  __shared__ short Bs[2][2][128][64];
  const int tid = threadIdx.x;
  const int w = tid >> 6, l = tid & 63;
  const int fr = l & 15, fg = l >> 4;
  const int wm = w >> 2, wn = w & 3;   // 2M x 4N wave grid

  // XCD-bijective swizzle (grid % 8 == 0 for our launches)
  const int q8 = gridDim.x >> 3;
  const int wg = (blockIdx.x & 7) * q8 + (blockIdx.x >> 3);
  const int bm = wg / nbn, bn = wg % nbn;
  const size_t brow = (size_t)bm << 8;
  const int bcol = bn << 8;
  const int NT = K >> 6;

  // staging: thread covers (row = j*64 + (tid>>3), 16B slot = tid&7);
  // source octet pre-swizzled: oct = slot ^ (row&7)  (j*64 == 0 mod 8)
  const int srow = tid >> 3;                    // 0..63
  const int soct = (tid & 7) ^ (srow & 7);
  // fragment phys slot: (kk*4+fg) ^ (fr&7), in shorts *8
  const int sx = fr & 7;

  f32x4 acc[8][4] = {};

#define STAGE_A(bufv, halfv, kt)                                               \
  {                                                                            \
    _Pragma("unroll") for (int j = 0; j < 2; ++j) {                            \
      const short* g = A + (brow + (halfv)*128 + j * 64 + srow) * (size_t)K +  \
                       (kt)*64 + soct * 8;                                     \
      gload_lds16(g, (char*)&As[bufv][halfv][j * 64 + w * 8][0]);              \
    }                                                                          \
  }
#define STAGE_B(bufv, halfv, kt)                                               \
  {                                                                            \
    _Pragma("unroll") for (int j = 0; j < 2; ++j) {                            \
      const short* g = BT +                                                    \
                       ((size_t)(bcol + (halfv)*128 + j * 64 + srow)) * K +    \
                       (kt)*64 + soct * 8;                                     \
      gload_lds16(g, (char*)&Bs[bufv][halfv][j * 64 + w * 8][0]);              \
    }                                                                          \
  }

  // prologue: full tile 0
  STAGE_A(0, 0, 0); STAGE_B(0, 0, 0); STAGE_A(0, 1, 0); STAGE_B(0, 1, 0);
  VMW(0);
  BAR();

  const int bhalf = wn >> 1, brow2 = (wn & 1) * 64;

  for (int t = 0; t < NT; ++t) {
    const int buf = t & 1, nbuf = buf ^ 1;
    bf16x8 bfr[4][2];
#pragma unroll
    for (int p = 0; p < 4; ++p) {
      // --- register subtile loads (compiler ds_read_b128) ---
      bf16x8 afr[2][2];
#pragma unroll
      for (int i = 0; i < 2; ++i)
#pragma unroll
        for (int kk = 0; kk < 2; ++kk)
          afr[i][kk] = *(const bf16x8*)
              &As[buf][wm][(2 * p + i) * 16 + fr][((kk * 4 + fg) ^ sx) * 8];
      if (p == 0) {
#pragma unroll
        for (int nf = 0; nf < 4; ++nf)
#pragma unroll
          for (int kk = 0; kk < 2; ++kk)
            bfr[nf][kk] = *(const bf16x8*)
                &Bs[buf][bhalf][brow2 + nf * 16 + fr][((kk * 4 + fg) ^ sx) * 8];
      }
      // --- stage next tile's halves early (p0: h0, p1: h1) ---
      if (t + 1 < NT) {
        if (p == 0) { STAGE_A(nbuf, 0, t + 1); STAGE_B(nbuf, 0, t + 1); }
        else if (p == 1) { STAGE_A(nbuf, 1, t + 1); STAGE_B(nbuf, 1, t + 1); }
      }
      if (p == 0) { LKW(8); }
      BAR();
      __builtin_amdgcn_s_setprio(1);
#pragma unroll
      for (int i = 0; i < 2; ++i)
#pragma unroll
        for (int nf = 0; nf < 4; ++nf)
#pragma unroll
          for (int kk = 0; kk < 2; ++kk)
            acc[2 * p + i][nf] = __builtin_amdgcn_mfma_f32_16x16x32_bf16(
                afr[i][kk], bfr[nf][kk], acc[2 * p + i][nf], 0, 0, 0);
      __builtin_amdgcn_s_setprio(0);
      if (p == 3 && t + 1 < NT) { VMW(0); }  // waits only on >=2-phase-old loads
      BAR();
    }
  }
#undef STAGE_A
#undef STAGE_B

  // epilogue: bias + store
#pragma unroll
  for (int nf = 0; nf < 4; ++nf) {
    const int col = bcol + wn * 64 + nf * 16 + fr;
    const float bv = bias[col];
#pragma unroll
    for (int mf = 0; mf < 8; ++mf) {
      const size_t row = brow + (size_t)(wm * 128 + mf * 16 + fg * 4);
#pragma unroll
      for (int r = 0; r < 4; ++r) {
        const float v = acc[mf][nf][r] + bv;
        if (F32OUT)
          ((float*)Cout)[(row + r) * (size_t)N + col] = v;
        else
          ((short*)Cout)[(row + r) * (size_t)N + col] = f2bf(v);
      }
    }
  }
}

// ---------------- fused anti-causal flash attention (keep k >= q) ----------------
// (unchanged from R4/R5/R6 — verified)
__global__ __launch_bounds__(256) void k_attn(
    const short* __restrict__ qkv, short* __restrict__ outc, int Bn, int S) {
  __shared__ short Ks[128][64];   // 16B slots XOR-swizzled within 128B rows
  __shared__ short Vt[64][136];   // V^T, padded pitch

  const int tid = threadIdx.x;
  const int w = tid >> 6, l = tid & 63;
  const int fr = l & 15, fg = l >> 4;

  const int tq = blockIdx.x >> 7;        // 0..15, longest work first
  const int bh = blockIdx.x & 127;
  const int h = bh & 15, b = bh >> 4;
  const int q0 = tq << 6;

  const size_t rowbase = (size_t)b * S;
  const int qcol = q0 + w * 16 + fr;

  bf16x8 qf[2];
  {
    const short* qp = qkv + (rowbase + qcol) * 3072 + h * 64 + fg * 8;
    qf[0] = *(const bf16x8*)qp;
    qf[1] = *(const bf16x8*)(qp + 32);
  }

  f32x4 o[4] = {};
  float m2 = -3.0e38f, ls = 0.0f;

  const short* Kbase = qkv + rowbase * 3072 + 1024 + h * 64;
  const short* Vbase = qkv + rowbase * 3072 + 2048 + h * 64;
  const float C2 = 0.04508422f;  // log2(e)/sqrt(1024)

  const int c0 = tq >> 1;
  for (int c = c0; c < 8; ++c) {
    const int k0 = c << 7;
    {
      int r8 = l >> 3, slot = l & 7;
#pragma unroll
      for (int j = 0; j < 4; ++j) {
        int ch = w * 4 + j;
        int row = ch * 8 + r8;
        int d = (slot ^ (row & 7)) << 3;
        gload_lds16(Kbase + (size_t)(k0 + row) * 3072 + d,
                    (char*)&Ks[0][0] + ch * 1024);
      }
    }
    {
      int db = (tid >> 4) << 2;
#pragma unroll
      for (int kh = 0; kh < 2; ++kh) {
        int kb = ((tid & 15) << 2) + (kh << 6);
        const short* vp = Vbase + (size_t)(k0 + kb) * 3072 + db;
        short4v r0 = *(const short4v*)(vp);
        short4v r1 = *(const short4v*)(vp + 3072);
        short4v r2 = *(const short4v*)(vp + 2 * 3072);
        short4v r3 = *(const short4v*)(vp + 3 * 3072);
        short4v t0 = {r0.x, r1.x, r2.x, r3.x};
        short4v t1 = {r0.y, r1.y, r2.y, r3.y};
        short4v t2 = {r0.z, r1.z, r2.z, r3.z};
        short4v t3 = {r0.w, r1.w, r2.w, r3.w};
        *(short4v*)&Vt[db + 0][kb] = t0;
        *(short4v*)&Vt[db + 1][kb] = t1;
        *(short4v*)&Vt[db + 2][kb] = t2;
        *(short4v*)&Vt[db + 3][kb] = t3;
      }
    }
    __syncthreads();

    f32x4 st[8];
#pragma unroll
    for (int kb = 0; kb < 8; ++kb) {
      f32x4 z = {0.f, 0.f, 0.f, 0.f};
      int row = kb * 16 + fr;
      int sw = row & 7;
      bf16x8 kf0 = *(const bf16x8*)&Ks[row][(fg ^ sw) << 3];
      bf16x8 kf1 = *(const bf16x8*)&Ks[row][((4 + fg) ^ sw) << 3];
      z = __builtin_amdgcn_mfma_f32_16x16x32_bf16(kf0, qf[0], z, 0, 0, 0);
      z = __builtin_amdgcn_mfma_f32_16x16x32_bf16(kf1, qf[1], z, 0, 0, 0);
      st[kb] = z;
    }

    const bool masked = (c == c0);
    float pm = -3.0e38f;
#pragma unroll
    for (int kb = 0; kb < 8; ++kb)
#pragma unroll
      for (int r = 0; r < 4; ++r) {
        float s = st[kb][r] * C2;
        if (masked) {
          int kg = k0 + kb * 16 + fg * 4 + r;
          s = (kg < qcol) ? -3.0e38f : s;
        }
        st[kb][r] = s;
        pm = fmaxf(pm, s);
      }
    pm = fmaxf(pm, __shfl_xor(pm, 16, 64));
    pm = fmaxf(pm, __shfl_xor(pm, 32, 64));

    bool skip = __all(pm - m2 <= 8.0f);
    float mnew = skip ? m2 : fmaxf(m2, pm);
    float psum = 0.f;
#pragma unroll
    for (int kb = 0; kb < 8; ++kb)
#pragma unroll
      for (int r = 0; r < 4; ++r) {
        float e = exp2f(st[kb][r] - mnew);
        st[kb][r] = e;
        psum += e;
      }
    psum += __shfl_xor(psum, 16, 64);
    psum += __shfl_xor(psum, 32, 64);
    if (skip) {
      ls += psum;
    } else {
      float scl = exp2f(m2 - mnew);
      ls = ls * scl + psum;
      m2 = mnew;
#pragma unroll
      for (int r = 0; r < 4; ++r) {
        float so = __shfl(scl, fg * 4 + r, 64);
#pragma unroll
        for (int f = 0; f < 4; ++f) o[f][r] *= so;
      }
    }

#pragma unroll
    for (int kb2 = 0; kb2 < 4; ++kb2) {
      bf16x8 pa = {f2bf(st[2 * kb2][0]),     f2bf(st[2 * kb2][1]),
                   f2bf(st[2 * kb2][2]),     f2bf(st[2 * kb2][3]),
                   f2bf(st[2 * kb2 + 1][0]), f2bf(st[2 * kb2 + 1][1]),
                   f2bf(st[2 * kb2 + 1][2]), f2bf(st[2 * kb2 + 1][3])};
#pragma unroll
      for (int f = 0; f < 4; ++f) {
        short4v v0 = *(const short4v*)&Vt[f * 16 + fr][kb2 * 32 + fg * 4];
        short4v v1 = *(const short4v*)&Vt[f * 16 + fr][kb2 * 32 + 16 + fg * 4];
        bf16x8 vb = {v0.x, v0.y, v0.z, v0.w, v1.x, v1.y, v1.z, v1.w};
        o[f] = __builtin_amdgcn_mfma_f32_16x16x32_bf16(pa, vb, o[f], 0, 0, 0);
      }
    }
    __syncthreads();
  }

#pragma unroll
  for (int r = 0; r < 4; ++r) {
    float denom = __shfl(ls, fg * 4 + r, 64);
    float inv = 1.0f / denom;
    size_t orow = rowbase + (size_t)(q0 + w * 16 + fg * 4 + r);
    short* op = outc + orow * 1024 + h * 64 + fr;
#pragma unroll
    for (int f = 0; f < 4; ++f) op[f * 16] = f2bf(o[f][r] * inv);
  }
}

extern "C" void kernel_launch(void* const* d_in, const int* in_sizes, int n_in,
                              void* d_out, int out_size, void* d_ws,
                              size_t ws_size, hipStream_t stream) {
  const float* x = (const float*)d_in[0];
  const float* Wc = (const float*)d_in[1];
  const float* bc = (const float*)d_in[2];
  const float* Wo = (const float*)d_in[3];
  const float* bo = (const float*)d_in[4];
  float* out = (float*)d_out;

  const int Bn = 8, S = 1024, D = 1024;
  const int M = Bn * S;  // 8192

  char* ws = (char*)d_ws;
  short* xb  = (short*)(ws);                               // 16 MB
  short* wct = (short*)(ws + (size_t)16 * 1024 * 1024);    // 6 MB  [3072][1024]
  short* wot = (short*)(ws + (size_t)22 * 1024 * 1024);    // 2 MB  [1024][1024]
  short* qkv = (short*)(ws + (size_t)24 * 1024 * 1024);    // 48 MB [8192][3072]
  short* cat = (short*)(ws + (size_t)72 * 1024 * 1024);    // 16 MB [8192][1024]

  k_f32_to_bf16<<<(M * D / 4 + 255) / 256, 256, 0, stream>>>(x, xb, M * D / 4);
  {
    dim3 g(3 * D / 64, D / 64);
    k_transpose_bf16<<<g, 256, 0, stream>>>(Wc, wct, D, 3 * D);
  }
  {
    dim3 g(D / 64, D / 64);
    k_transpose_bf16<<<g, 256, 0, stream>>>(Wo, wot, D, D);
  }
  k_g256<false><<<(M / 256) * (3 * D / 256), 512, 0, stream>>>(
      xb, wct, bc, qkv, M, 3 * D, D, 3 * D / 256);
  k_attn<<<16 * 128, 256, 0, stream>>>(qkv, cat, Bn, S);
  k_g256<true><<<(M / 256) * (D / 256), 512, 0, stream>>>(
      cat, wot, bo, out, M, D, D, D / 256);
}

// Round 9
// 186.733 us; speedup vs baseline: 1.0202x; 1.0202x over previous
//
#include <hip/hip_runtime.h>
#include <stdint.h>

typedef __attribute__((ext_vector_type(8))) short  bf16x8;
typedef __attribute__((ext_vector_type(4))) short  short4v;
typedef __attribute__((ext_vector_type(4))) float  f32x4;
typedef __attribute__((ext_vector_type(4))) float  float4v;

#define VMW(N) asm volatile("s_waitcnt vmcnt(" #N ")" ::: "memory")
#define LKW(N) asm volatile("s_waitcnt lgkmcnt(" #N ")" ::: "memory")
#define BAR()  asm volatile("s_barrier" ::: "memory")

__device__ __forceinline__ short f2bf(float f) {
  union { float f; uint32_t u; } c; c.f = f;
  uint32_t u = c.u;
  uint32_t r = (u + 0x7FFFu + ((u >> 16) & 1u)) >> 16;
  return (short)(uint16_t)r;
}

__device__ __forceinline__ void gload_lds16(const void* g, void* l) {
  __builtin_amdgcn_global_load_lds(
      (const __attribute__((address_space(1))) void*)g,
      (__attribute__((address_space(3))) void*)l, 16, 0, 0);
}

// ---------------- f32 -> bf16 (vectorized, 4 elems/thread) ----------------
__global__ __launch_bounds__(256) void k_f32_to_bf16(
    const float* __restrict__ in, short* __restrict__ out, int n4) {
  int i = blockIdx.x * 256 + threadIdx.x;
  if (i >= n4) return;
  float4v v = *(const float4v*)(in + (size_t)i * 4);
  short4v o;
  o.x = f2bf(v.x); o.y = f2bf(v.y); o.z = f2bf(v.z); o.w = f2bf(v.w);
  *(short4v*)(out + (size_t)i * 4) = o;
}

// ------------- transpose f32[R][C] -> bf16[C][R] (64x64 LDS tiles) -------------
__global__ __launch_bounds__(256) void k_transpose_bf16(
    const float* __restrict__ in, short* __restrict__ out, int R, int C) {
  __shared__ short tile[64][65];
  int bc = blockIdx.x * 64, br = blockIdx.y * 64;
  int tc = threadIdx.x & 63, tr = threadIdx.x >> 6;  // tr 0..3
#pragma unroll
  for (int i = 0; i < 64; i += 4)
    tile[tc][tr + i] = f2bf(in[(size_t)(br + tr + i) * C + bc + tc]);
  __syncthreads();
#pragma unroll
  for (int i = 0; i < 64; i += 4)
    out[(size_t)(bc + tr + i) * R + br + tc] = tile[tr + i][tc];
}

// ---------- GEMM 256x256, one-barrier-per-K-tile read-ahead pipeline ----------
// BK=64, 512 threads = 8 waves (2M x 4N), per-wave C = 128x64 (acc[8][4]).
// LDS: As/Bs [2 dbuf][2 half][128][64] shorts = 128 KB total.
// Per K-tile t (4 quadrant-phases, ONE barrier):
//  p0: stage ALL of tile t+1 -> SM[nbuf]; issue afr(q1); MFMA q0
//  p1: issue afr(q2); MFMA q1        p2: issue afr(q3); MFMA q2
//  p3: LKW(0) [all buf reads serviced]; VMW(0) [t+1 stages landed, ~3 phases
//      old => cheap]; BAR; issue afr(q0,t+1) from nbuf; MFMA q3; reload bfr
//      (t+1) — WAR on bfr regs orders it after q3's MFMA automatically.
// Ledger: buffer b's last reads drained by every wave's LKW(0) before the
// barrier; stages into b only occur after that barrier (next tile's p0). ✓
// sched_barrier(0) pins read-issue clusters ahead of each MFMA cluster.
// Data mapping (swizzle slot^(row&7) both sides, quadrants, epilogue) is
// identical to the R7-verified kernel — only the schedule changed.
template <bool F32OUT>
__global__ __launch_bounds__(512) void k_g256(
    const short* __restrict__ A, const short* __restrict__ BT,
    const float* __restrict__ bias, void* __restrict__ Cout,
    int M, int N, int K, int nbn) {
  __shared__ short As[2][2][128][64];
  __shared__ short Bs[2][2][128][64];
  const int tid = threadIdx.x;
  const int w = tid >> 6, l = tid & 63;
  const int fr = l & 15, fg = l >> 4;
  const int wm = w >> 2, wn = w & 3;   // 2M x 4N wave grid

  // XCD-bijective swizzle (grid % 8 == 0 for our launches)
  const int q8 = gridDim.x >> 3;
  const int wg = (blockIdx.x & 7) * q8 + (blockIdx.x >> 3);
  const int bm = wg / nbn, bn = wg % nbn;
  const size_t brow = (size_t)bm << 8;
  const int bcol = bn << 8;
  const int NT = K >> 6;

  // staging: thread covers (row = j*64 + (tid>>3), 16B slot = tid&7);
  // source octet pre-swizzled: oct = slot ^ (row&7)
  const int srow = tid >> 3;                    // 0..63
  const int soct = (tid & 7) ^ (srow & 7);
  const int sx = fr & 7;                        // frag un-swizzle key

  f32x4 acc[8][4] = {};
  bf16x8 afr0[2][2], afr1[2][2], bfr[4][2];

#define STAGE_A(bufv, halfv, kt)                                               \
  {                                                                            \
    _Pragma("unroll") for (int j = 0; j < 2; ++j) {                            \
      const short* g = A + (brow + (halfv)*128 + j * 64 + srow) * (size_t)K +  \
                       (kt)*64 + soct * 8;                                     \
      gload_lds16(g, (char*)&As[bufv][halfv][j * 64 + w * 8][0]);              \
    }                                                                          \
  }
#define STAGE_B(bufv, halfv, kt)                                               \
  {                                                                            \
    _Pragma("unroll") for (int j = 0; j < 2; ++j) {                            \
      const short* g = BT +                                                    \
                       ((size_t)(bcol + (halfv)*128 + j * 64 + srow)) * K +    \
                       (kt)*64 + soct * 8;                                     \
      gload_lds16(g, (char*)&Bs[bufv][halfv][j * 64 + w * 8][0]);              \
    }                                                                          \
  }
#define READ_A(dst, bufv, q)                                                   \
  {                                                                            \
    _Pragma("unroll") for (int i = 0; i < 2; ++i)                              \
        _Pragma("unroll") for (int kk = 0; kk < 2; ++kk)                       \
            dst[i][kk] = *(const bf16x8*)&As[bufv][wm][(2 * (q) + i) * 16 +    \
                                                      fr][((kk * 4 + fg) ^ sx) * 8]; \
  }
#define READ_B(bufv)                                                           \
  {                                                                            \
    _Pragma("unroll") for (int nf = 0; nf < 4; ++nf)                           \
        _Pragma("unroll") for (int kk = 0; kk < 2; ++kk)                       \
            bfr[nf][kk] = *(const bf16x8*)&Bs[bufv][wn >> 1][(wn & 1) * 64 +   \
                                                 nf * 16 + fr][((kk * 4 + fg) ^ sx) * 8]; \
  }
#define MFMA_Q(q, src)                                                         \
  {                                                                            \
    _Pragma("unroll") for (int i = 0; i < 2; ++i)                              \
        _Pragma("unroll") for (int nf = 0; nf < 4; ++nf)                       \
            _Pragma("unroll") for (int kk = 0; kk < 2; ++kk)                   \
                acc[2 * (q) + i][nf] = __builtin_amdgcn_mfma_f32_16x16x32_bf16( \
                    src[i][kk], bfr[nf][kk], acc[2 * (q) + i][nf], 0, 0, 0);   \
  }

  // prologue: stage tile 0 into SM[0], then first fragments
  STAGE_A(0, 0, 0); STAGE_A(0, 1, 0); STAGE_B(0, 0, 0); STAGE_B(0, 1, 0);
  VMW(0);
  BAR();
  READ_A(afr0, 0, 0);
  READ_B(0);

  for (int t = 0; t < NT; ++t) {
    const int buf = t & 1, nbuf = buf ^ 1;
    const bool more = (t + 1 < NT);
    // ---- p0 ----
    if (more) {
      STAGE_A(nbuf, 0, t + 1); STAGE_A(nbuf, 1, t + 1);
      STAGE_B(nbuf, 0, t + 1); STAGE_B(nbuf, 1, t + 1);
    }
    READ_A(afr1, buf, 1);
    __builtin_amdgcn_sched_barrier(0);
    __builtin_amdgcn_s_setprio(1);
    MFMA_Q(0, afr0);
    __builtin_amdgcn_s_setprio(0);
    // ---- p1 ----
    READ_A(afr0, buf, 2);
    __builtin_amdgcn_sched_barrier(0);
    __builtin_amdgcn_s_setprio(1);
    MFMA_Q(1, afr1);
    __builtin_amdgcn_s_setprio(0);
    // ---- p2 ----
    READ_A(afr1, buf, 3);
    __builtin_amdgcn_sched_barrier(0);
    __builtin_amdgcn_s_setprio(1);
    MFMA_Q(2, afr0);
    __builtin_amdgcn_s_setprio(0);
    // ---- p3 ----
    LKW(0);            // every buf-read of this wave serviced
    if (more) VMW(0);  // t+1 stages landed (issued at p0, ~3 phases old)
    BAR();             // after this, ALL waves' buf reads done + nbuf valid
    if (more) READ_A(afr0, nbuf, 0);
    __builtin_amdgcn_sched_barrier(0);
    __builtin_amdgcn_s_setprio(1);
    MFMA_Q(3, afr1);
    __builtin_amdgcn_s_setprio(0);
    if (more) READ_B(nbuf);  // WAR on bfr: scheduled after q3's MFMA reads
  }
#undef STAGE_A
#undef STAGE_B
#undef READ_A
#undef READ_B
#undef MFMA_Q

  // epilogue: bias + store
#pragma unroll
  for (int nf = 0; nf < 4; ++nf) {
    const int col = bcol + wn * 64 + nf * 16 + fr;
    const float bv = bias[col];
#pragma unroll
    for (int mf = 0; mf < 8; ++mf) {
      const size_t row = brow + (size_t)(wm * 128 + mf * 16 + fg * 4);
#pragma unroll
      for (int r = 0; r < 4; ++r) {
        const float v = acc[mf][nf][r] + bv;
        if (F32OUT)
          ((float*)Cout)[(row + r) * (size_t)N + col] = v;
        else
          ((short*)Cout)[(row + r) * (size_t)N + col] = f2bf(v);
      }
    }
  }
}

// ---------------- fused anti-causal flash attention (keep k >= q) ----------------
// (unchanged from R4-R8 — verified)
__global__ __launch_bounds__(256) void k_attn(
    const short* __restrict__ qkv, short* __restrict__ outc, int Bn, int S) {
  __shared__ short Ks[128][64];   // 16B slots XOR-swizzled within 128B rows
  __shared__ short Vt[64][136];   // V^T, padded pitch

  const int tid = threadIdx.x;
  const int w = tid >> 6, l = tid & 63;
  const int fr = l & 15, fg = l >> 4;

  const int tq = blockIdx.x >> 7;        // 0..15, longest work first
  const int bh = blockIdx.x & 127;
  const int h = bh & 15, b = bh >> 4;
  const int q0 = tq << 6;

  const size_t rowbase = (size_t)b * S;
  const int qcol = q0 + w * 16 + fr;

  bf16x8 qf[2];
  {
    const short* qp = qkv + (rowbase + qcol) * 3072 + h * 64 + fg * 8;
    qf[0] = *(const bf16x8*)qp;
    qf[1] = *(const bf16x8*)(qp + 32);
  }

  f32x4 o[4] = {};
  float m2 = -3.0e38f, ls = 0.0f;

  const short* Kbase = qkv + rowbase * 3072 + 1024 + h * 64;
  const short* Vbase = qkv + rowbase * 3072 + 2048 + h * 64;
  const float C2 = 0.04508422f;  // log2(e)/sqrt(1024)

  const int c0 = tq >> 1;
  for (int c = c0; c < 8; ++c) {
    const int k0 = c << 7;
    {
      int r8 = l >> 3, slot = l & 7;
#pragma unroll
      for (int j = 0; j < 4; ++j) {
        int ch = w * 4 + j;
        int row = ch * 8 + r8;
        int d = (slot ^ (row & 7)) << 3;
        gload_lds16(Kbase + (size_t)(k0 + row) * 3072 + d,
                    (char*)&Ks[0][0] + ch * 1024);
      }
    }
    {
      int db = (tid >> 4) << 2;
#pragma unroll
      for (int kh = 0; kh < 2; ++kh) {
        int kb = ((tid & 15) << 2) + (kh << 6);
        const short* vp = Vbase + (size_t)(k0 + kb) * 3072 + db;
        short4v r0 = *(const short4v*)(vp);
        short4v r1 = *(const short4v*)(vp + 3072);
        short4v r2 = *(const short4v*)(vp + 2 * 3072);
        short4v r3 = *(const short4v*)(vp + 3 * 3072);
        short4v t0 = {r0.x, r1.x, r2.x, r3.x};
        short4v t1 = {r0.y, r1.y, r2.y, r3.y};
        short4v t2 = {r0.z, r1.z, r2.z, r3.z};
        short4v t3 = {r0.w, r1.w, r2.w, r3.w};
        *(short4v*)&Vt[db + 0][kb] = t0;
        *(short4v*)&Vt[db + 1][kb] = t1;
        *(short4v*)&Vt[db + 2][kb] = t2;
        *(short4v*)&Vt[db + 3][kb] = t3;
      }
    }
    __syncthreads();

    f32x4 st[8];
#pragma unroll
    for (int kb = 0; kb < 8; ++kb) {
      f32x4 z = {0.f, 0.f, 0.f, 0.f};
      int row = kb * 16 + fr;
      int sw = row & 7;
      bf16x8 kf0 = *(const bf16x8*)&Ks[row][(fg ^ sw) << 3];
      bf16x8 kf1 = *(const bf16x8*)&Ks[row][((4 + fg) ^ sw) << 3];
      z = __builtin_amdgcn_mfma_f32_16x16x32_bf16(kf0, qf[0], z, 0, 0, 0);
      z = __builtin_amdgcn_mfma_f32_16x16x32_bf16(kf1, qf[1], z, 0, 0, 0);
      st[kb] = z;
    }

    const bool masked = (c == c0);
    float pm = -3.0e38f;
#pragma unroll
    for (int kb = 0; kb < 8; ++kb)
#pragma unroll
      for (int r = 0; r < 4; ++r) {
        float s = st[kb][r] * C2;
        if (masked) {
          int kg = k0 + kb * 16 + fg * 4 + r;
          s = (kg < qcol) ? -3.0e38f : s;
        }
        st[kb][r] = s;
        pm = fmaxf(pm, s);
      }
    pm = fmaxf(pm, __shfl_xor(pm, 16, 64));
    pm = fmaxf(pm, __shfl_xor(pm, 32, 64));

    bool skip = __all(pm - m2 <= 8.0f);
    float mnew = skip ? m2 : fmaxf(m2, pm);
    float psum = 0.f;
#pragma unroll
    for (int kb = 0; kb < 8; ++kb)
#pragma unroll
      for (int r = 0; r < 4; ++r) {
        float e = exp2f(st[kb][r] - mnew);
        st[kb][r] = e;
        psum += e;
      }
    psum += __shfl_xor(psum, 16, 64);
    psum += __shfl_xor(psum, 32, 64);
    if (skip) {
      ls += psum;
    } else {
      float scl = exp2f(m2 - mnew);
      ls = ls * scl + psum;
      m2 = mnew;
#pragma unroll
      for (int r = 0; r < 4; ++r) {
        float so = __shfl(scl, fg * 4 + r, 64);
#pragma unroll
        for (int f = 0; f < 4; ++f) o[f][r] *= so;
      }
    }

#pragma unroll
    for (int kb2 = 0; kb2 < 4; ++kb2) {
      bf16x8 pa = {f2bf(st[2 * kb2][0]),     f2bf(st[2 * kb2][1]),
                   f2bf(st[2 * kb2][2]),     f2bf(st[2 * kb2][3]),
                   f2bf(st[2 * kb2 + 1][0]), f2bf(st[2 * kb2 + 1][1]),
                   f2bf(st[2 * kb2 + 1][2]), f2bf(st[2 * kb2 + 1][3])};
#pragma unroll
      for (int f = 0; f < 4; ++f) {
        short4v v0 = *(const short4v*)&Vt[f * 16 + fr][kb2 * 32 + fg * 4];
        short4v v1 = *(const short4v*)&Vt[f * 16 + fr][kb2 * 32 + 16 + fg * 4];
        bf16x8 vb = {v0.x, v0.y, v0.z, v0.w, v1.x, v1.y, v1.z, v1.w};
        o[f] = __builtin_amdgcn_mfma_f32_16x16x32_bf16(pa, vb, o[f], 0, 0, 0);
      }
    }
    __syncthreads();
  }

#pragma unroll
  for (int r = 0; r < 4; ++r) {
    float denom = __shfl(ls, fg * 4 + r, 64);
    float inv = 1.0f / denom;
    size_t orow = rowbase + (size_t)(q0 + w * 16 + fg * 4 + r);
    short* op = outc + orow * 1024 + h * 64 + fr;
#pragma unroll
    for (int f = 0; f < 4; ++f) op[f * 16] = f2bf(o[f][r] * inv);
  }
}

extern "C" void kernel_launch(void* const* d_in, const int* in_sizes, int n_in,
                              void* d_out, int out_size, void* d_ws,
                              size_t ws_size, hipStream_t stream) {
  const float* x = (const float*)d_in[0];
  const float* Wc = (const float*)d_in[1];
  const float* bc = (const float*)d_in[2];
  const float* Wo = (const float*)d_in[3];
  const float* bo = (const float*)d_in[4];
  float* out = (float*)d_out;

  const int Bn = 8, S = 1024, D = 1024;
  const int M = Bn * S;  // 8192

  char* ws = (char*)d_ws;
  short* xb  = (short*)(ws);                               // 16 MB
  short* wct = (short*)(ws + (size_t)16 * 1024 * 1024);    // 6 MB  [3072][1024]
  short* wot = (short*)(ws + (size_t)22 * 1024 * 1024);    // 2 MB  [1024][1024]
  short* qkv = (short*)(ws + (size_t)24 * 1024 * 1024);    // 48 MB [8192][3072]
  short* cat = (short*)(ws + (size_t)72 * 1024 * 1024);    // 16 MB [8192][1024]

  k_f32_to_bf16<<<(M * D / 4 + 255) / 256, 256, 0, stream>>>(x, xb, M * D / 4);
  {
    dim3 g(3 * D / 64, D / 64);
    k_transpose_bf16<<<g, 256, 0, stream>>>(Wc, wct, D, 3 * D);
  }
  {
    dim3 g(D / 64, D / 64);
    k_transpose_bf16<<<g, 256, 0, stream>>>(Wo, wot, D, D);
  }
  k_g256<false><<<(M / 256) * (3 * D / 256), 512, 0, stream>>>(
      xb, wct, bc, qkv, M, 3 * D, D, 3 * D / 256);
  k_attn<<<16 * 128, 256, 0, stream>>>(qkv, cat, Bn, S);
  k_g256<true><<<(M / 256) * (D / 256), 512, 0, stream>>>(
      cat, wot, bo, out, M, D, D, D / 256);
}

// Round 10
// 176.195 us; speedup vs baseline: 1.0812x; 1.0598x over previous
//
#include <hip/hip_runtime.h>
#include <stdint.h>

typedef __attribute__((ext_vector_type(8))) short  bf16x8;
typedef __attribute__((ext_vector_type(4))) short  short4v;
typedef __attribute__((ext_vector_type(4))) float  f32x4;
typedef __attribute__((ext_vector_type(4))) float  float4v;

#define VMW(N) asm volatile("s_waitcnt vmcnt(" #N ")" ::: "memory")
#define BAR()  asm volatile("s_barrier" ::: "memory")

__device__ __forceinline__ short f2bf(float f) {
  union { float f; uint32_t u; } c; c.f = f;
  uint32_t u = c.u;
  uint32_t r = (u + 0x7FFFu + ((u >> 16) & 1u)) >> 16;
  return (short)(uint16_t)r;
}

__device__ __forceinline__ void gload_lds16(const void* g, void* l) {
  __builtin_amdgcn_global_load_lds(
      (const __attribute__((address_space(1))) void*)g,
      (__attribute__((address_space(3))) void*)l, 16, 0, 0);
}

// ---------------- f32 -> bf16 (vectorized, 4 elems/thread) ----------------
__global__ __launch_bounds__(256) void k_f32_to_bf16(
    const float* __restrict__ in, short* __restrict__ out, int n4) {
  int i = blockIdx.x * 256 + threadIdx.x;
  if (i >= n4) return;
  float4v v = *(const float4v*)(in + (size_t)i * 4);
  short4v o;
  o.x = f2bf(v.x); o.y = f2bf(v.y); o.z = f2bf(v.z); o.w = f2bf(v.w);
  *(short4v*)(out + (size_t)i * 4) = o;
}

// ------------- transpose f32[R][C] -> bf16[C][R] (64x64 LDS tiles) -------------
__global__ __launch_bounds__(256) void k_transpose_bf16(
    const float* __restrict__ in, short* __restrict__ out, int R, int C) {
  __shared__ short tile[64][65];
  int bc = blockIdx.x * 64, br = blockIdx.y * 64;
  int tc = threadIdx.x & 63, tr = threadIdx.x >> 6;  // tr 0..3
#pragma unroll
  for (int i = 0; i < 64; i += 4)
    tile[tc][tr + i] = f2bf(in[(size_t)(br + tr + i) * C + bc + tc]);
  __syncthreads();
#pragma unroll
  for (int i = 0; i < 64; i += 4)
    out[(size_t)(bc + tr + i) * R + br + tc] = tile[tr + i][tc];
}

// ------------- GEMM (R6-verified best): 128x128, BK=64, two-phase counted ------
template <bool F32OUT>
__global__ __launch_bounds__(256) void k_gemm2(
    const short* __restrict__ A, const short* __restrict__ BT,
    const float* __restrict__ bias, void* __restrict__ Cout,
    int M, int N, int K, int nbn) {
  __shared__ short SM[2][2][2][128][32];  // [buf][mat(A=0,B=1)][kh][row][kcol]
  const int tid = threadIdx.x;
  const int w = tid >> 6, l = tid & 63;
  const int fr = l & 15, fg = l >> 4;
  const int wm = w >> 1, wn = w & 1;

  const int q8 = gridDim.x >> 3;
  const int wg = (blockIdx.x & 7) * q8 + (blockIdx.x >> 3);
  const int bm = wg / nbn, bn = wg % nbn;
  const size_t brow = (size_t)bm << 7;
  const int bcol = bn << 7;

  const int NT = K >> 6;

  const int srow = l >> 2;
  const int soct = (l & 3) ^ ((l >> 3) & 3);
  const short* aG = A + (brow + srow) * (size_t)K + soct * 8;
  const short* bG = BT + ((size_t)(bcol + srow)) * K + soct * 8;
  const int slot8 = ((fg ^ ((fr >> 1) & 3)) << 3);

  f32x4 acc[4][4] = {};

#pragma unroll
  for (int s = 0; s < 6; ++s) {
    const int t = s >> 2, tau = s & 3, buf = t & 1, mat = tau & 1, kh = tau >> 1;
    const int kbase = t * 64 + kh * 32;
    const short* g0 = (mat ? bG : aG) + kbase;
#pragma unroll
    for (int j = 0; j < 2; ++j) {
      const int r0 = (w * 2 + j) * 16;
      gload_lds16(g0 + (size_t)r0 * K, (char*)&SM[buf][mat][kh][r0][0]);
    }
  }
  VMW(8);
  BAR();

  int sidx = 6;
  for (int t = 0; t < NT; ++t) {
    const int buf = t & 1;
#pragma unroll
    for (int p = 0; p < 2; ++p) {
      const int kh = p;
#pragma unroll
      for (int s = 0; s < 2; ++s) {
        if (sidx < NT * 4) {
          const int ts = sidx >> 2, tau = sidx & 3;
          const int sb = ts & 1, mat = tau & 1, skh = tau >> 1;
          const int kbase = ts * 64 + skh * 32;
          const short* g0 = (mat ? bG : aG) + kbase;
#pragma unroll
          for (int j = 0; j < 2; ++j) {
            const int r0 = (w * 2 + j) * 16;
            gload_lds16(g0 + (size_t)r0 * K, (char*)&SM[sb][mat][skh][r0][0]);
          }
          ++sidx;
        }
      }
      bf16x8 af[4], bf[4];
#pragma unroll
      for (int m = 0; m < 4; ++m)
        af[m] = *(const bf16x8*)&SM[buf][0][kh][wm * 64 + m * 16 + fr][slot8];
#pragma unroll
      for (int n = 0; n < 4; ++n)
        bf[n] = *(const bf16x8*)&SM[buf][1][kh][wn * 64 + n * 16 + fr][slot8];
      BAR();
      __builtin_amdgcn_s_setprio(1);
#pragma unroll
      for (int m = 0; m < 4; ++m)
#pragma unroll
        for (int n = 0; n < 4; ++n)
          acc[m][n] = __builtin_amdgcn_mfma_f32_16x16x32_bf16(
              af[m], bf[n], acc[m][n], 0, 0, 0);
      __builtin_amdgcn_s_setprio(0);
      if (!(t == NT - 1 && p == 1)) {
        if (t == NT - 1 && p == 0) { VMW(0); }
        else if (t == NT - 2 && p == 1) { VMW(4); }
        else { VMW(8); }
        BAR();
      }
    }
  }

#pragma unroll
  for (int n = 0; n < 4; ++n) {
    const int col = bcol + wn * 64 + n * 16 + fr;
    const float bv = bias[col];
#pragma unroll
    for (int i = 0; i < 4; ++i) {
      const size_t row = brow + (size_t)(wm * 64 + i * 16 + fg * 4);
#pragma unroll
      for (int r = 0; r < 4; ++r) {
        const float v = acc[i][n][r] + bv;
        if (F32OUT)
          ((float*)Cout)[(row + r) * (size_t)N + col] = v;
        else
          ((short*)Cout)[(row + r) * (size_t)N + col] = f2bf(v);
      }
    }
  }
}

// ---------------- fused anti-causal flash attention (keep k >= q) ----------------
// R4-verified math + T14 async staging: Ks double-buffered via global_load_lds;
// V loaded to REGISTERS one tile ahead, written to LDS after the top barrier
// (which also proves all waves finished PV of the previous tile -> Vt reuse safe).
// Per step: VMW(0) [loads are a full step old] -> BAR -> Vt write -> issue
// K(c+1)+V(c+1) -> QK(c) -> softmax -> BAR -> PV(c).
__global__ __launch_bounds__(256) void k_attn(
    const short* __restrict__ qkv, short* __restrict__ outc, int Bn, int S) {
  __shared__ short Ks[2][128][64];  // 16B slots XOR-swizzled within 128B rows
  __shared__ short Vt[64][136];     // V^T, padded pitch

  const int tid = threadIdx.x;
  const int w = tid >> 6, l = tid & 63;
  const int fr = l & 15, fg = l >> 4;

  const int tq = blockIdx.x >> 7;        // 0..15, longest work first (LPT)
  const int bh = blockIdx.x & 127;
  const int h = bh & 15, b = bh >> 4;
  const int q0 = tq << 6;

  const size_t rowbase = (size_t)b * S;
  const int qcol = q0 + w * 16 + fr;

  bf16x8 qf[2];
  {
    const short* qp = qkv + (rowbase + qcol) * 3072 + h * 64 + fg * 8;
    qf[0] = *(const bf16x8*)qp;
    qf[1] = *(const bf16x8*)(qp + 32);
  }

  f32x4 o[4] = {};
  float m2 = -3.0e38f, ls = 0.0f;

  const short* Kbase = qkv + rowbase * 3072 + 1024 + h * 64;
  const short* Vbase = qkv + rowbase * 3072 + 2048 + h * 64;
  const float C2 = 0.04508422f;  // log2(e)/sqrt(1024)

  const int r8 = l >> 3, slot = l & 7;
  const int vdb = (tid >> 4) << 2;       // 0..60, V col block

#define STAGE_K(c, bufv)                                                       \
  {                                                                            \
    const int k0s = (c) << 7;                                                  \
    _Pragma("unroll") for (int j = 0; j < 4; ++j) {                            \
      int ch = w * 4 + j;                                                      \
      int row = ch * 8 + r8;                                                   \
      int d = (slot ^ (row & 7)) << 3;                                         \
      gload_lds16(Kbase + (size_t)(k0s + row) * 3072 + d,                      \
                  (char*)&Ks[bufv][0][0] + ch * 1024);                         \
    }                                                                          \
  }
#define LOAD_V(c, vr)                                                          \
  {                                                                            \
    const int k0s = (c) << 7;                                                  \
    _Pragma("unroll") for (int kh = 0; kh < 2; ++kh) {                         \
      int kb = ((tid & 15) << 2) + (kh << 6);                                  \
      const short* vp = Vbase + (size_t)(k0s + kb) * 3072 + vdb;               \
      vr[kh][0] = *(const short4v*)(vp);                                       \
      vr[kh][1] = *(const short4v*)(vp + 3072);                                \
      vr[kh][2] = *(const short4v*)(vp + 2 * 3072);                            \
      vr[kh][3] = *(const short4v*)(vp + 3 * 3072);                            \
    }                                                                          \
  }

  const int c0 = tq >> 1;
  short4v vr[2][4];
  STAGE_K(c0, 0);
  LOAD_V(c0, vr);
  int cur = 0;

  for (int c = c0; c < 8; ++c) {
    const int k0 = c << 7;
    VMW(0);   // K(c) staged + vr loaded (issued a full step earlier after c0)
    BAR();    // all waves: stages visible AND previous PV done -> Vt reusable

    // write V(c) from regs into Vt (4x4 transpose), then issue next-tile loads
#pragma unroll
    for (int kh = 0; kh < 2; ++kh) {
      int kb = ((tid & 15) << 2) + (kh << 6);
      short4v t0 = {vr[kh][0].x, vr[kh][1].x, vr[kh][2].x, vr[kh][3].x};
      short4v t1 = {vr[kh][0].y, vr[kh][1].y, vr[kh][2].y, vr[kh][3].y};
      short4v t2 = {vr[kh][0].z, vr[kh][1].z, vr[kh][2].z, vr[kh][3].z};
      short4v t3 = {vr[kh][0].w, vr[kh][1].w, vr[kh][2].w, vr[kh][3].w};
      *(short4v*)&Vt[vdb + 0][kb] = t0;
      *(short4v*)&Vt[vdb + 1][kb] = t1;
      *(short4v*)&Vt[vdb + 2][kb] = t2;
      *(short4v*)&Vt[vdb + 3][kb] = t3;
    }
    if (c + 1 < 8) {
      STAGE_K(c + 1, cur ^ 1);
      LOAD_V(c + 1, vr);
    }

    // S^T = K * Q^T from Ks[cur]
    f32x4 st[8];
#pragma unroll
    for (int kb = 0; kb < 8; ++kb) {
      f32x4 z = {0.f, 0.f, 0.f, 0.f};
      int row = kb * 16 + fr;
      int sw = row & 7;
      bf16x8 kf0 = *(const bf16x8*)&Ks[cur][row][(fg ^ sw) << 3];
      bf16x8 kf1 = *(const bf16x8*)&Ks[cur][row][((4 + fg) ^ sw) << 3];
      z = __builtin_amdgcn_mfma_f32_16x16x32_bf16(kf0, qf[0], z, 0, 0, 0);
      z = __builtin_amdgcn_mfma_f32_16x16x32_bf16(kf1, qf[1], z, 0, 0, 0);
      st[kb] = z;
    }

    // scale + mask + online softmax (base-2, defer-max)
    const bool masked = (c == c0);
    float pm = -3.0e38f;
#pragma unroll
    for (int kb = 0; kb < 8; ++kb)
#pragma unroll
      for (int r = 0; r < 4; ++r) {
        float s = st[kb][r] * C2;
        if (masked) {
          int kg = k0 + kb * 16 + fg * 4 + r;
          s = (kg < qcol) ? -3.0e38f : s;
        }
        st[kb][r] = s;
        pm = fmaxf(pm, s);
      }
    pm = fmaxf(pm, __shfl_xor(pm, 16, 64));
    pm = fmaxf(pm, __shfl_xor(pm, 32, 64));

    bool skip = __all(pm - m2 <= 8.0f);
    float mnew = skip ? m2 : fmaxf(m2, pm);
    float psum = 0.f;
#pragma unroll
    for (int kb = 0; kb < 8; ++kb)
#pragma unroll
      for (int r = 0; r < 4; ++r) {
        float e = exp2f(st[kb][r] - mnew);
        st[kb][r] = e;
        psum += e;
      }
    psum += __shfl_xor(psum, 16, 64);
    psum += __shfl_xor(psum, 32, 64);
    if (skip) {
      ls += psum;
    } else {
      float scl = exp2f(m2 - mnew);
      ls = ls * scl + psum;
      m2 = mnew;
#pragma unroll
      for (int r = 0; r < 4; ++r) {
        float so = __shfl(scl, fg * 4 + r, 64);
#pragma unroll
        for (int f = 0; f < 4; ++f) o[f][r] *= so;
      }
    }

    BAR();  // Vt(c) writes visible to all waves

    // PV via k-permuted 16x16x32 mfma (P already A-layout, zero cross-lane)
#pragma unroll
    for (int kb2 = 0; kb2 < 4; ++kb2) {
      bf16x8 pa = {f2bf(st[2 * kb2][0]),     f2bf(st[2 * kb2][1]),
                   f2bf(st[2 * kb2][2]),     f2bf(st[2 * kb2][3]),
                   f2bf(st[2 * kb2 + 1][0]), f2bf(st[2 * kb2 + 1][1]),
                   f2bf(st[2 * kb2 + 1][2]), f2bf(st[2 * kb2 + 1][3])};
#pragma unroll
      for (int f = 0; f < 4; ++f) {
        short4v v0 = *(const short4v*)&Vt[f * 16 + fr][kb2 * 32 + fg * 4];
        short4v v1 = *(const short4v*)&Vt[f * 16 + fr][kb2 * 32 + 16 + fg * 4];
        bf16x8 vb = {v0.x, v0.y, v0.z, v0.w, v1.x, v1.y, v1.z, v1.w};
        o[f] = __builtin_amdgcn_mfma_f32_16x16x32_bf16(pa, vb, o[f], 0, 0, 0);
      }
    }
    cur ^= 1;
  }
#undef STAGE_K
#undef LOAD_V

  // normalize + store bf16
#pragma unroll
  for (int r = 0; r < 4; ++r) {
    float denom = __shfl(ls, fg * 4 + r, 64);
    float inv = 1.0f / denom;
    size_t orow = rowbase + (size_t)(q0 + w * 16 + fg * 4 + r);
    short* op = outc + orow * 1024 + h * 64 + fr;
#pragma unroll
    for (int f = 0; f < 4; ++f) op[f * 16] = f2bf(o[f][r] * inv);
  }
}

extern "C" void kernel_launch(void* const* d_in, const int* in_sizes, int n_in,
                              void* d_out, int out_size, void* d_ws,
                              size_t ws_size, hipStream_t stream) {
  const float* x = (const float*)d_in[0];
  const float* Wc = (const float*)d_in[1];
  const float* bc = (const float*)d_in[2];
  const float* Wo = (const float*)d_in[3];
  const float* bo = (const float*)d_in[4];
  float* out = (float*)d_out;

  const int Bn = 8, S = 1024, D = 1024;
  const int M = Bn * S;  // 8192

  char* ws = (char*)d_ws;
  short* xb  = (short*)(ws);                               // 16 MB
  short* wct = (short*)(ws + (size_t)16 * 1024 * 1024);    // 6 MB  [3072][1024]
  short* wot = (short*)(ws + (size_t)22 * 1024 * 1024);    // 2 MB  [1024][1024]
  short* qkv = (short*)(ws + (size_t)24 * 1024 * 1024);    // 48 MB [8192][3072]
  short* cat = (short*)(ws + (size_t)72 * 1024 * 1024);    // 16 MB [8192][1024]

  k_f32_to_bf16<<<(M * D / 4 + 255) / 256, 256, 0, stream>>>(x, xb, M * D / 4);
  {
    dim3 g(3 * D / 64, D / 64);
    k_transpose_bf16<<<g, 256, 0, stream>>>(Wc, wct, D, 3 * D);
  }
  {
    dim3 g(D / 64, D / 64);
    k_transpose_bf16<<<g, 256, 0, stream>>>(Wo, wot, D, D);
  }
  k_gemm2<false><<<(M / 128) * (3 * D / 128), 256, 0, stream>>>(
      xb, wct, bc, qkv, M, 3 * D, D, 3 * D / 128);
  k_attn<<<16 * 128, 256, 0, stream>>>(qkv, cat, Bn, S);
  k_gemm2<true><<<(M / 128) * (D / 128), 256, 0, stream>>>(
      cat, wot, bo, out, M, D, D, D / 128);
}

// Round 11
// 161.967 us; speedup vs baseline: 1.1761x; 1.0878x over previous
//
#include <hip/hip_runtime.h>
#include <stdint.h>

typedef __attribute__((ext_vector_type(8))) short  bf16x8;
typedef __attribute__((ext_vector_type(4))) short  short4v;
typedef __attribute__((ext_vector_type(4))) float  f32x4;
typedef __attribute__((ext_vector_type(4))) float  float4v;

#define VMW(N) asm volatile("s_waitcnt vmcnt(" #N ")" ::: "memory")
#define BAR()  asm volatile("s_barrier" ::: "memory")

__device__ __forceinline__ short f2bf(float f) {
  union { float f; uint32_t u; } c; c.f = f;
  uint32_t u = c.u;
  uint32_t r = (u + 0x7FFFu + ((u >> 16) & 1u)) >> 16;
  return (short)(uint16_t)r;
}

// hardware bf16 convert (compiler emits v_cvt_pk_bf16_f32 for pairs)
__device__ __forceinline__ short f2bf_hw(float f) {
  return __builtin_bit_cast(short, (__bf16)f);
}

__device__ __forceinline__ void gload_lds16(const void* g, void* l) {
  __builtin_amdgcn_global_load_lds(
      (const __attribute__((address_space(1))) void*)g,
      (__attribute__((address_space(3))) void*)l, 16, 0, 0);
}

// ---------------- f32 -> bf16 (vectorized, 4 elems/thread) ----------------
__global__ __launch_bounds__(256) void k_f32_to_bf16(
    const float* __restrict__ in, short* __restrict__ out, int n4) {
  int i = blockIdx.x * 256 + threadIdx.x;
  if (i >= n4) return;
  float4v v = *(const float4v*)(in + (size_t)i * 4);
  short4v o;
  o.x = f2bf(v.x); o.y = f2bf(v.y); o.z = f2bf(v.z); o.w = f2bf(v.w);
  *(short4v*)(out + (size_t)i * 4) = o;
}

// ------------- transpose f32[R][C] -> bf16[C][R] (64x64 LDS tiles) -------------
__global__ __launch_bounds__(256) void k_transpose_bf16(
    const float* __restrict__ in, short* __restrict__ out, int R, int C) {
  __shared__ short tile[64][65];
  int bc = blockIdx.x * 64, br = blockIdx.y * 64;
  int tc = threadIdx.x & 63, tr = threadIdx.x >> 6;  // tr 0..3
#pragma unroll
  for (int i = 0; i < 64; i += 4)
    tile[tc][tr + i] = f2bf(in[(size_t)(br + tr + i) * C + bc + tc]);
  __syncthreads();
#pragma unroll
  for (int i = 0; i < 64; i += 4)
    out[(size_t)(bc + tr + i) * R + br + tc] = tile[tr + i][tc];
}

// ------------- GEMM (R6-verified best): 128x128, BK=64, two-phase counted ------
template <bool F32OUT>
__global__ __launch_bounds__(256) void k_gemm2(
    const short* __restrict__ A, const short* __restrict__ BT,
    const float* __restrict__ bias, void* __restrict__ Cout,
    int M, int N, int K, int nbn) {
  __shared__ short SM[2][2][2][128][32];  // [buf][mat(A=0,B=1)][kh][row][kcol]
  const int tid = threadIdx.x;
  const int w = tid >> 6, l = tid & 63;
  const int fr = l & 15, fg = l >> 4;
  const int wm = w >> 1, wn = w & 1;

  const int q8 = gridDim.x >> 3;
  const int wg = (blockIdx.x & 7) * q8 + (blockIdx.x >> 3);
  const int bm = wg / nbn, bn = wg % nbn;
  const size_t brow = (size_t)bm << 7;
  const int bcol = bn << 7;

  const int NT = K >> 6;

  const int srow = l >> 2;
  const int soct = (l & 3) ^ ((l >> 3) & 3);
  const short* aG = A + (brow + srow) * (size_t)K + soct * 8;
  const short* bG = BT + ((size_t)(bcol + srow)) * K + soct * 8;
  const int slot8 = ((fg ^ ((fr >> 1) & 3)) << 3);

  f32x4 acc[4][4] = {};

#pragma unroll
  for (int s = 0; s < 6; ++s) {
    const int t = s >> 2, tau = s & 3, buf = t & 1, mat = tau & 1, kh = tau >> 1;
    const int kbase = t * 64 + kh * 32;
    const short* g0 = (mat ? bG : aG) + kbase;
#pragma unroll
    for (int j = 0; j < 2; ++j) {
      const int r0 = (w * 2 + j) * 16;
      gload_lds16(g0 + (size_t)r0 * K, (char*)&SM[buf][mat][kh][r0][0]);
    }
  }
  VMW(8);
  BAR();

  int sidx = 6;
  for (int t = 0; t < NT; ++t) {
    const int buf = t & 1;
#pragma unroll
    for (int p = 0; p < 2; ++p) {
      const int kh = p;
#pragma unroll
      for (int s = 0; s < 2; ++s) {
        if (sidx < NT * 4) {
          const int ts = sidx >> 2, tau = sidx & 3;
          const int sb = ts & 1, mat = tau & 1, skh = tau >> 1;
          const int kbase = ts * 64 + skh * 32;
          const short* g0 = (mat ? bG : aG) + kbase;
#pragma unroll
          for (int j = 0; j < 2; ++j) {
            const int r0 = (w * 2 + j) * 16;
            gload_lds16(g0 + (size_t)r0 * K, (char*)&SM[sb][mat][skh][r0][0]);
          }
          ++sidx;
        }
      }
      bf16x8 af[4], bf[4];
#pragma unroll
      for (int m = 0; m < 4; ++m)
        af[m] = *(const bf16x8*)&SM[buf][0][kh][wm * 64 + m * 16 + fr][slot8];
#pragma unroll
      for (int n = 0; n < 4; ++n)
        bf[n] = *(const bf16x8*)&SM[buf][1][kh][wn * 64 + n * 16 + fr][slot8];
      BAR();
      __builtin_amdgcn_s_setprio(1);
#pragma unroll
      for (int m = 0; m < 4; ++m)
#pragma unroll
        for (int n = 0; n < 4; ++n)
          acc[m][n] = __builtin_amdgcn_mfma_f32_16x16x32_bf16(
              af[m], bf[n], acc[m][n], 0, 0, 0);
      __builtin_amdgcn_s_setprio(0);
      if (!(t == NT - 1 && p == 1)) {
        if (t == NT - 1 && p == 0) { VMW(0); }
        else if (t == NT - 2 && p == 1) { VMW(4); }
        else { VMW(8); }
        BAR();
      }
    }
  }

#pragma unroll
  for (int n = 0; n < 4; ++n) {
    const int col = bcol + wn * 64 + n * 16 + fr;
    const float bv = bias[col];
#pragma unroll
    for (int i = 0; i < 4; ++i) {
      const size_t row = brow + (size_t)(wm * 64 + i * 16 + fg * 4);
#pragma unroll
      for (int r = 0; r < 4; ++r) {
        const float v = acc[i][n][r] + bv;
        if (F32OUT)
          ((float*)Cout)[(row + r) * (size_t)N + col] = v;
        else
          ((short*)Cout)[(row + r) * (size_t)N + col] = f2bf(v);
      }
    }
  }
}

// ---------------- fused anti-causal flash attention (keep k >= q) ----------------
// R6-verified structure (single Ks buffer, __syncthreads, 4 blocks/CU) with the
// softmax slimmed for the VALU bottleneck measured in R10 (VALUBusy 58%):
//  - softmax scale folded into Q (pre-scaled by log2e/sqrt(D) at load)
//  - NO max tracking: scaled scores bounded (|s|<=46) => exp2 can't overflow,
//    P can't underflow bf16; l is a pure per-lane running sum, reduced once.
//  - hardware bf16 convert (v_cvt_pk_bf16_f32) instead of 4-op manual round.
__global__ __launch_bounds__(256) void k_attn(
    const short* __restrict__ qkv, short* __restrict__ outc, int Bn, int S) {
  __shared__ short Ks[128][64];   // 16B slots XOR-swizzled within 128B rows
  __shared__ short Vt[64][136];   // V^T, padded pitch

  const int tid = threadIdx.x;
  const int w = tid >> 6, l = tid & 63;
  const int fr = l & 15, fg = l >> 4;

  const int tq = blockIdx.x >> 7;        // 0..15, longest work first (LPT)
  const int bh = blockIdx.x & 127;
  const int h = bh & 15, b = bh >> 4;
  const int q0 = tq << 6;

  const size_t rowbase = (size_t)b * S;
  const int qcol = q0 + w * 16 + fr;

  // load Q and pre-scale by log2(e)/sqrt(1024): QK^T output is the exp2 arg
  bf16x8 qf[2];
  {
    const short* qp = qkv + (rowbase + qcol) * 3072 + h * 64 + fg * 8;
    qf[0] = *(const bf16x8*)qp;
    qf[1] = *(const bf16x8*)(qp + 32);
    const float C2 = 0.04508422f;
#pragma unroll
    for (int j = 0; j < 8; ++j) {
      union { float f; uint32_t u; } ca, cb;
      ca.u = ((uint32_t)(uint16_t)qf[0][j]) << 16;
      cb.u = ((uint32_t)(uint16_t)qf[1][j]) << 16;
      qf[0][j] = f2bf_hw(ca.f * C2);
      qf[1][j] = f2bf_hw(cb.f * C2);
    }
  }

  f32x4 o[4] = {};
  float lacc = 0.0f;

  const short* Kbase = qkv + rowbase * 3072 + 1024 + h * 64;
  const short* Vbase = qkv + rowbase * 3072 + 2048 + h * 64;

  const int c0 = tq >> 1;
  for (int c = c0; c < 8; ++c) {
    const int k0 = c << 7;
    // stage K: 128 rows x 128B, source pre-swizzled so LDS slot = octet^(row&7)
    {
      int r8 = l >> 3, slot = l & 7;
#pragma unroll
      for (int j = 0; j < 4; ++j) {
        int ch = w * 4 + j;
        int row = ch * 8 + r8;
        int d = (slot ^ (row & 7)) << 3;
        gload_lds16(Kbase + (size_t)(k0 + row) * 3072 + d,
                    (char*)&Ks[0][0] + ch * 1024);
      }
    }
    // stage V^T: 128 k x 64 d (reg 4x4 transpose, two k-halves)
    {
      int db = (tid >> 4) << 2;
#pragma unroll
      for (int kh = 0; kh < 2; ++kh) {
        int kb = ((tid & 15) << 2) + (kh << 6);
        const short* vp = Vbase + (size_t)(k0 + kb) * 3072 + db;
        short4v r0 = *(const short4v*)(vp);
        short4v r1 = *(const short4v*)(vp + 3072);
        short4v r2 = *(const short4v*)(vp + 2 * 3072);
        short4v r3 = *(const short4v*)(vp + 3 * 3072);
        short4v t0 = {r0.x, r1.x, r2.x, r3.x};
        short4v t1 = {r0.y, r1.y, r2.y, r3.y};
        short4v t2 = {r0.z, r1.z, r2.z, r3.z};
        short4v t3 = {r0.w, r1.w, r2.w, r3.w};
        *(short4v*)&Vt[db + 0][kb] = t0;
        *(short4v*)&Vt[db + 1][kb] = t1;
        *(short4v*)&Vt[db + 2][kb] = t2;
        *(short4v*)&Vt[db + 3][kb] = t3;
      }
    }
    __syncthreads();

    // S^T = K * Q^T  (st[kb][r]: k = k0+kb*16+fg*4+r, q = qcol), pre-scaled
    f32x4 st[8];
#pragma unroll
    for (int kb = 0; kb < 8; ++kb) {
      f32x4 z = {0.f, 0.f, 0.f, 0.f};
      int row = kb * 16 + fr;
      int sw = row & 7;
      bf16x8 kf0 = *(const bf16x8*)&Ks[row][(fg ^ sw) << 3];
      bf16x8 kf1 = *(const bf16x8*)&Ks[row][((4 + fg) ^ sw) << 3];
      z = __builtin_amdgcn_mfma_f32_16x16x32_bf16(kf0, qf[0], z, 0, 0, 0);
      z = __builtin_amdgcn_mfma_f32_16x16x32_bf16(kf1, qf[1], z, 0, 0, 0);
      st[kb] = z;
    }

    // no-max softmax: P = exp2(st); masked lanes -> 0; l = running lane sum
    const bool masked = (c == c0);
#pragma unroll
    for (int kb = 0; kb < 8; ++kb)
#pragma unroll
      for (int r = 0; r < 4; ++r) {
        float e = exp2f(st[kb][r]);
        if (masked) {
          int kg = k0 + kb * 16 + fg * 4 + r;
          e = (kg < qcol) ? 0.0f : e;
        }
        st[kb][r] = e;
        lacc += e;
      }

    // PV via k-permuted 16x16x32 mfma (P already A-layout, zero cross-lane)
#pragma unroll
    for (int kb2 = 0; kb2 < 4; ++kb2) {
      bf16x8 pa = {f2bf_hw(st[2 * kb2][0]),     f2bf_hw(st[2 * kb2][1]),
                   f2bf_hw(st[2 * kb2][2]),     f2bf_hw(st[2 * kb2][3]),
                   f2bf_hw(st[2 * kb2 + 1][0]), f2bf_hw(st[2 * kb2 + 1][1]),
                   f2bf_hw(st[2 * kb2 + 1][2]), f2bf_hw(st[2 * kb2 + 1][3])};
#pragma unroll
      for (int f = 0; f < 4; ++f) {
        short4v v0 = *(const short4v*)&Vt[f * 16 + fr][kb2 * 32 + fg * 4];
        short4v v1 = *(const short4v*)&Vt[f * 16 + fr][kb2 * 32 + 16 + fg * 4];
        bf16x8 vb = {v0.x, v0.y, v0.z, v0.w, v1.x, v1.y, v1.z, v1.w};
        o[f] = __builtin_amdgcn_mfma_f32_16x16x32_bf16(pa, vb, o[f], 0, 0, 0);
      }
    }
    __syncthreads();
  }

  // reduce l across fg groups once, then normalize + store bf16
  lacc += __shfl_xor(lacc, 16, 64);
  lacc += __shfl_xor(lacc, 32, 64);
#pragma unroll
  for (int r = 0; r < 4; ++r) {
    float denom = __shfl(lacc, fg * 4 + r, 64);
    float inv = 1.0f / denom;
    size_t orow = rowbase + (size_t)(q0 + w * 16 + fg * 4 + r);
    short* op = outc + orow * 1024 + h * 64 + fr;
#pragma unroll
    for (int f = 0; f < 4; ++f) op[f * 16] = f2bf(o[f][r] * inv);
  }
}

extern "C" void kernel_launch(void* const* d_in, const int* in_sizes, int n_in,
                              void* d_out, int out_size, void* d_ws,
                              size_t ws_size, hipStream_t stream) {
  const float* x = (const float*)d_in[0];
  const float* Wc = (const float*)d_in[1];
  const float* bc = (const float*)d_in[2];
  const float* Wo = (const float*)d_in[3];
  const float* bo = (const float*)d_in[4];
  float* out = (float*)d_out;

  const int Bn = 8, S = 1024, D = 1024;
  const int M = Bn * S;  // 8192

  char* ws = (char*)d_ws;
  short* xb  = (short*)(ws);                               // 16 MB
  short* wct = (short*)(ws + (size_t)16 * 1024 * 1024);    // 6 MB  [3072][1024]
  short* wot = (short*)(ws + (size_t)22 * 1024 * 1024);    // 2 MB  [1024][1024]
  short* qkv = (short*)(ws + (size_t)24 * 1024 * 1024);    // 48 MB [8192][3072]
  short* cat = (short*)(ws + (size_t)72 * 1024 * 1024);    // 16 MB [8192][1024]

  k_f32_to_bf16<<<(M * D / 4 + 255) / 256, 256, 0, stream>>>(x, xb, M * D / 4);
  {
    dim3 g(3 * D / 64, D / 64);
    k_transpose_bf16<<<g, 256, 0, stream>>>(Wc, wct, D, 3 * D);
  }
  {
    dim3 g(D / 64, D / 64);
    k_transpose_bf16<<<g, 256, 0, stream>>>(Wo, wot, D, D);
  }
  k_gemm2<false><<<(M / 128) * (3 * D / 128), 256, 0, stream>>>(
      xb, wct, bc, qkv, M, 3 * D, D, 3 * D / 128);
  k_attn<<<16 * 128, 256, 0, stream>>>(qkv, cat, Bn, S);
  k_gemm2<true><<<(M / 128) * (D / 128), 256, 0, stream>>>(
      cat, wot, bo, out, M, D, D, D / 128);
}